// Round 9
// baseline (362.594 us; speedup 1.0000x reference)
//
#include <hip/hip_runtime.h>
#include <hip/hip_bf16.h>

// Problem constants: S=2048, B=4, E=512, ENC=32, H=8, dq=4, dv=64, scale=0.5
#define S_LEN 2048
#define B_SZ 4
#define E_DIM 512
#define H_NUM 8
#define DQ 4
#define DV 64

typedef __attribute__((ext_vector_type(8))) short s16x8;   // 8 bf16
typedef __attribute__((ext_vector_type(4))) float f32x4;   // MFMA C/D
typedef unsigned short u16;

__device__ __forceinline__ u16 f2b(float x) {
    __hip_bfloat16 h = __float2bfloat16(x);
    return *(u16*)&h;
}

// ---------------------------------------------------------------------------
// K0: cast query + 3 weight matrices to bf16 (grid-stride, 8 elems/thread)
// ---------------------------------------------------------------------------
__global__ __launch_bounds__(256) void cast_bf16(
    const float* __restrict__ q,  u16* __restrict__ qb,
    const float* __restrict__ w1, u16* __restrict__ w1b,
    const float* __restrict__ w2, u16* __restrict__ w2b,
    const float* __restrict__ w3, u16* __restrict__ w3b)
{
    const int NQ = S_LEN * B_SZ * E_DIM / 8;   // 524288
    const int N1 = 64 * E_DIM / 8;             // 4096
    const int N2 = E_DIM * E_DIM / 8;          // 32768
    const int total = NQ + N1 + 2 * N2;
    for (int g = blockIdx.x * 256 + threadIdx.x; g < total; g += gridDim.x * 256) {
        const float* src; u16* dst; int off;
        if (g < NQ)                { src = q;  dst = qb;  off = g; }
        else if (g < NQ + N1)      { src = w1; dst = w1b; off = g - NQ; }
        else if (g < NQ + N1 + N2) { src = w2; dst = w2b; off = g - NQ - N1; }
        else                       { src = w3; dst = w3b; off = g - NQ - N1 - N2; }
        float4 a = ((const float4*)src)[(size_t)off * 2];
        float4 b = ((const float4*)src)[(size_t)off * 2 + 1];
        s16x8 o;
        o[0] = f2b(a.x); o[1] = f2b(a.y); o[2] = f2b(a.z); o[3] = f2b(a.w);
        o[4] = f2b(b.x); o[5] = f2b(b.y); o[6] = f2b(b.z); o[7] = f2b(b.w);
        ((s16x8*)dst)[off] = o;
    }
}

// ---------------------------------------------------------------------------
// bf16 MFMA GEMM: C[M x N] = A[M x K] @ W[N x K]^T (+ bias, f32)
// BM=128, BN=64, BK=64; 256 thr = 4 waves (2M x 2N); wave tile 64x32.
// MODE 0: plain C + b1.
// MODE 1: QKV epilogue scatter: q*0.5 / k -> f32 [b][h][s][dq];
//         v -> bf16 TRANSPOSED vtg[b][h][d][s] (L2 merges the 2B scatter:
//         each (d, 32-s) line is fully written within one block).
// MFMA 16x16x32_bf16 maps (HW-verified R6):
//   A elem j of lane l = A[l&15][(l>>4)*8+j]
//   B elem j of lane l = B[(l>>4)*8+j][l&15]
//   C/D: col=l&15, row=(l>>4)*4+reg
// ---------------------------------------------------------------------------
template <int MODE>
__global__ __launch_bounds__(256) void gemm_mfma(
    const u16* __restrict__ Abf,
    const u16* __restrict__ W1, const float* __restrict__ b1,
    const u16* __restrict__ W2, const float* __restrict__ b2,
    float* __restrict__ C,
    float* __restrict__ qs, float* __restrict__ ks,
    u16* __restrict__ vtg,
    int N, int K)
{
    constexpr int PP = 72;
    __shared__ __align__(16) u16 As[128][PP];  // 18 KB
    __shared__ __align__(16) u16 Bs[64][PP];   //  9 KB

    const int m0 = blockIdx.x * 128;
    const int n0 = blockIdx.y * 64;
    const int tid = threadIdx.x;
    const int w = tid >> 6, lane = tid & 63;
    const int wm = w >> 1, wn = w & 1;
    const int fr = lane & 15;
    const int fk = (lane >> 4) << 3;

    const u16* Wsel; int nbase;
    if (MODE == 0 || n0 < 64) { Wsel = W1; nbase = n0; }
    else                      { Wsel = W2; nbase = n0 - 64; }

    const int ar = tid >> 1, ah = (tid & 1) << 5;
    const int br = tid >> 2, bq = (tid & 3) << 4;

    f32x4 acc[4][2];
#pragma unroll
    for (int mt = 0; mt < 4; ++mt)
#pragma unroll
        for (int nt = 0; nt < 2; ++nt) acc[mt][nt] = (f32x4){0.f, 0.f, 0.f, 0.f};

    for (int kp = 0; kp < K; kp += 64) {
        const s16x8* ap = (const s16x8*)&Abf[(size_t)(m0 + ar) * K + kp + ah];
        s16x8 a0 = ap[0], a1 = ap[1], a2 = ap[2], a3 = ap[3];
        const s16x8* bp = (const s16x8*)&Wsel[(size_t)(nbase + br) * K + kp + bq];
        s16x8 b0 = bp[0], b1v = bp[1];
        __syncthreads();
        *(s16x8*)&As[ar][ah + 0]  = a0;
        *(s16x8*)&As[ar][ah + 8]  = a1;
        *(s16x8*)&As[ar][ah + 16] = a2;
        *(s16x8*)&As[ar][ah + 24] = a3;
        *(s16x8*)&Bs[br][bq + 0]  = b0;
        *(s16x8*)&Bs[br][bq + 8]  = b1v;
        __syncthreads();

#pragma unroll
        for (int kb = 0; kb < 2; ++kb) {
            s16x8 bf0 = *(const s16x8*)&Bs[wn * 32 + fr][(kb << 5) + fk];
            s16x8 bf1 = *(const s16x8*)&Bs[wn * 32 + 16 + fr][(kb << 5) + fk];
#pragma unroll
            for (int mt = 0; mt < 4; ++mt) {
                s16x8 af = *(const s16x8*)&As[wm * 64 + mt * 16 + fr][(kb << 5) + fk];
                acc[mt][0] = __builtin_amdgcn_mfma_f32_16x16x32_bf16(af, bf0, acc[mt][0], 0, 0, 0);
                acc[mt][1] = __builtin_amdgcn_mfma_f32_16x16x32_bf16(af, bf1, acc[mt][1], 0, 0, 0);
            }
        }
    }

#pragma unroll
    for (int mt = 0; mt < 4; ++mt)
#pragma unroll
        for (int nt = 0; nt < 2; ++nt)
#pragma unroll
            for (int j = 0; j < 4; ++j) {
                int m = m0 + wm * 64 + mt * 16 + ((lane >> 4) << 2) + j;
                int c = n0 + wn * 32 + nt * 16 + fr;
                float val = acc[mt][nt][j];
                if (MODE == 0) {
                    C[(size_t)m * N + c] = val + b1[c];
                } else {
                    int s  = m >> 2;        // A row = s*B + b
                    int bb = m & 3;
                    if (c < 64) {
                        val += b1[c];
                        if (c < 32) {
                            qs[((((size_t)bb * H_NUM) + (c >> 2)) * S_LEN + s) * DQ + (c & 3)] = val * 0.5f;
                        } else {
                            int j2 = c - 32;
                            ks[((((size_t)bb * H_NUM) + (j2 >> 2)) * S_LEN + s) * DQ + (j2 & 3)] = val;
                        }
                    } else {
                        int j2 = c - 64;    // h*64 + d
                        val += b2[j2];
                        vtg[((((size_t)bb * H_NUM) + (j2 >> 6)) * DV + (j2 & 63)) * S_LEN + s] = f2b(val);
                    }
                }
            }
}

// ---------------------------------------------------------------------------
// K2: softmax denominators (unchanged from R7). No-max softmax is exact:
// Xavier-scale scores |s| < ~12, far from f32 exp overflow.
// ---------------------------------------------------------------------------
__global__ __launch_bounds__(256) void lsum_kernel(
    const float* __restrict__ qs, const float* __restrict__ ks,
    float* __restrict__ linv)
{
    const int bh = blockIdx.x;
    const int s0 = blockIdx.y * 64;
    const int sl = threadIdx.x >> 2;
    const int tq = threadIdx.x & 3;
    __shared__ float Ksm[S_LEN][DQ];
    __shared__ float part[64][4];
    const float* kp = ks + (size_t)bh * S_LEN * DQ;
    for (int i = threadIdx.x; i < S_LEN; i += 256)
        *(float4*)&Ksm[i][0] = *(const float4*)&kp[(size_t)i * DQ];
    __syncthreads();

    const float4 q = *(const float4*)&qs[((size_t)bh * S_LEN + s0 + sl) * DQ];
    float l = 0.f;
    const int t0 = tq * (S_LEN / 4);
#pragma unroll 4
    for (int t = t0; t < t0 + S_LEN / 4; ++t) {
        float4 kk = *(const float4*)&Ksm[t][0];
        float sc = q.x * kk.x + q.y * kk.y + q.z * kk.z + q.w * kk.w;
        l += __expf(sc);
    }
    part[sl][tq] = l;
    __syncthreads();
    if (threadIdx.x < 64) {
        float tsum = part[threadIdx.x][0] + part[threadIdx.x][1] +
                     part[threadIdx.x][2] + part[threadIdx.x][3];
        linv[(size_t)bh * S_LEN + s0 + threadIdx.x] = 1.0f / tsum;
    }
}

// ---------------------------------------------------------------------------
// K3: fused attention. 512 thr / 8 waves per (b, 32-row tile), chunk TT=64.
// Per chunk:
//   stage: Kc[h][t][4] f32 (wave w -> head w, 1 write);
//          vt[h][d][t] bf16 from pre-transposed vtg (8 b128 writes, no
//          in-kernel transpose)
//   score1 (aw only): thread (w,lane) owns (s=w+it*8, t=lane) for all 8
//          heads; linv hoisted to 32 regs; writes aw chunk coalesced
//   score2+PV: wave w recomputes head w's P directly in MFMA A-frag layout
//          (lane: s=fr+16m, t=fk+j; 16 Kc b128 reads, 32 exps, reg pack) ->
//          no P LDS round-trip; B-frags from vt (8 b128 reads)
// ---------------------------------------------------------------------------
__global__ __launch_bounds__(512) void attn_fused(
    const float* __restrict__ qs, const float* __restrict__ ks,
    const u16* __restrict__ vtg, const float* __restrict__ linv,
    float* __restrict__ aw, u16* __restrict__ ao)
{
    constexpr int TQ = 32, TT = 64, PP = 72;
    const int b = blockIdx.x;
    const int s0 = blockIdx.y * TQ;
    const int tid = threadIdx.x;
    const int w = tid >> 6;
    const int lane = tid & 63;

    __shared__ float Kc[H_NUM][TT][DQ];                 //  8 KB
    __shared__ float qt[H_NUM][TQ][DQ];                 //  4 KB
    __shared__ float linvs[H_NUM][TQ];                  //  1 KB
    __shared__ __align__(16) u16 vt[H_NUM][DV][PP];     // 72 KB

    if (tid < 256) {
        int h = tid >> 5, s = tid & 31;
        *(float4*)&qt[h][s][0] =
            *(const float4*)&qs[((((size_t)b * H_NUM) + h) * S_LEN + s0 + s) * DQ];
        linvs[h][s] = linv[(((size_t)b * H_NUM) + h) * S_LEN + s0 + s];
    }
    __syncthreads();

    const int fr = lane & 15;
    const int fk = (lane >> 4) << 3;

    // hoisted registers
    float lr[H_NUM][4];                 // linv for score1's (h, s=w+it*8)
#pragma unroll
    for (int h = 0; h < H_NUM; ++h)
#pragma unroll
        for (int it = 0; it < 4; ++it) lr[h][it] = linvs[h][w + (it << 3)];
    float4 qA0 = *(const float4*)&qt[w][fr][0];        // score2 rows
    float4 qA1 = *(const float4*)&qt[w][16 + fr][0];
    float lv0 = linvs[w][fr], lv1 = linvs[w][16 + fr];

    f32x4 acc[2][4];
#pragma unroll
    for (int m = 0; m < 2; ++m)
#pragma unroll
        for (int n = 0; n < 4; ++n) acc[m][n] = (f32x4){0.f, 0.f, 0.f, 0.f};

    const float* krow = ks + (((size_t)b * H_NUM) + w) * S_LEN * DQ;
    const u16* vrow = vtg + ((((size_t)b * H_NUM) + w) * DV + lane) * S_LEN;
    float* awrow = aw + ((size_t)b * S_LEN + s0) * S_LEN;

    for (int t0 = 0; t0 < S_LEN; t0 += TT) {
        __syncthreads();   // prev chunk's Kc/vt reads done

        // stage K chunk (wave w -> head w, lane -> t)
        *(float4*)&Kc[w][lane][0] = *(const float4*)&krow[(size_t)(t0 + lane) * DQ];
        // stage V^T chunk row-major (lane -> d row; 8 x 16B global + LDS b128)
#pragma unroll
        for (int i = 0; i < 8; ++i) {
            s16x8 vv = *(const s16x8*)(vrow + t0 + (i << 3));
            *(s16x8*)&vt[w][lane][i << 3] = vv;
        }
        __syncthreads();

        // score1: avg_weights only (exact f32 p)
        float awacc[4] = {0.f, 0.f, 0.f, 0.f};
#pragma unroll 2
        for (int h = 0; h < H_NUM; ++h) {
            float4 kk = *(const float4*)&Kc[h][lane][0];
#pragma unroll
            for (int it = 0; it < 4; ++it) {
                float4 q = *(const float4*)&qt[h][w + (it << 3)][0];
                float sc = q.x * kk.x + q.y * kk.y + q.z * kk.z + q.w * kk.w;
                awacc[it] += __expf(sc) * lr[h][it];
            }
        }
#pragma unroll
        for (int it = 0; it < 4; ++it)
            awrow[(size_t)(w + (it << 3)) * S_LEN + t0 + lane] = awacc[it] * 0.125f;

        // score2 + PV: head w, P in A-frag layout (s=fr+16m, t=fk+j)
#pragma unroll
        for (int kb = 0; kb < 2; ++kb) {
            s16x8 a0, a1;
#pragma unroll
            for (int j = 0; j < 8; ++j) {
                float4 kk = *(const float4*)&Kc[w][(kb << 5) + fk + j][0];
                float sc0 = qA0.x * kk.x + qA0.y * kk.y + qA0.z * kk.z + qA0.w * kk.w;
                float sc1 = qA1.x * kk.x + qA1.y * kk.y + qA1.z * kk.z + qA1.w * kk.w;
                a0[j] = (short)f2b(__expf(sc0) * lv0);
                a1[j] = (short)f2b(__expf(sc1) * lv1);
            }
#pragma unroll
            for (int n = 0; n < 4; ++n) {
                s16x8 bb = *(const s16x8*)&vt[w][(n << 4) + fr][(kb << 5) + fk];
                acc[0][n] = __builtin_amdgcn_mfma_f32_16x16x32_bf16(a0, bb, acc[0][n], 0, 0, 0);
                acc[1][n] = __builtin_amdgcn_mfma_f32_16x16x32_bf16(a1, bb, acc[1][n], 0, 0, 0);
            }
        }
    }

    // epilogue: bf16 ao; C/D map: s = m*16 + (lane>>4)*4 + j, d = n*16 + fr
#pragma unroll
    for (int m = 0; m < 2; ++m)
#pragma unroll
        for (int n = 0; n < 4; ++n)
#pragma unroll
            for (int j = 0; j < 4; ++j) {
                int s = (m << 4) + ((lane >> 4) << 2) + j;
                int d = (n << 4) + fr;
                ao[((size_t)(s0 + s) * B_SZ + b) * E_DIM + (w * DV + d)] =
                    f2b(acc[m][n][j]);
            }
}

// ---------------------------------------------------------------------------
extern "C" void kernel_launch(void* const* d_in, const int* in_sizes, int n_in,
                              void* d_out, int out_size, void* d_ws, size_t ws_size,
                              hipStream_t stream) {
    const float* query = (const float*)d_in[0];
    const float* ipw   = (const float*)d_in[1];
    const float* ipb   = (const float*)d_in[2];
    const float* vpw   = (const float*)d_in[3];
    const float* vpb   = (const float*)d_in[4];
    const float* opw   = (const float*)d_in[5];
    const float* opb   = (const float*)d_in[6];

    float* out_main = (float*)d_out;
    float* aw       = (float*)d_out + (size_t)S_LEN * B_SZ * E_DIM;

    // workspace carve-up
    const size_t NQKV = (size_t)B_SZ * H_NUM * S_LEN;   // 65536
    float* qs   = (float*)d_ws;                          // 1 MB
    float* ks   = qs + NQKV * DQ;                        // 1 MB
    float* linv = ks + NQKV * DQ;                        // 256 KB
    u16* vtg    = (u16*)(linv + NQKV);                   // 8 MB [b][h][d][s]
    u16* qbf    = vtg + (size_t)S_LEN * B_SZ * E_DIM;    // 8 MB
    u16* aobf   = qbf;   // alias: qbf dead after K1
    u16* ipwbf  = qbf + (size_t)S_LEN * B_SZ * E_DIM;
    u16* vpwbf  = ipwbf + 64 * E_DIM;
    u16* opwbf  = vpwbf + (size_t)E_DIM * E_DIM;

    // K0: cast query + weights to bf16
    cast_bf16<<<1024, 256, 0, stream>>>(query, qbf, ipw, ipwbf, vpw, vpwbf, opw, opwbf);

    // K1: fused QKV projection (MFMA, N=576; v written transposed)
    dim3 g1(8192 / 128, 576 / 64);
    gemm_mfma<1><<<g1, 256, 0, stream>>>(qbf, ipwbf, ipb, vpwbf, vpb,
                                         nullptr, qs, ks, vtg, 576, E_DIM);

    // K2: softmax denominators
    lsum_kernel<<<dim3(B_SZ * H_NUM, S_LEN / 64), 256, 0, stream>>>(qs, ks, linv);

    // K3: fused attention
    attn_fused<<<dim3(B_SZ, S_LEN / 32), 512, 0, stream>>>(qs, ks, vtg, linv, aw, aobf);

    // K4: out projection (MFMA)
    dim3 g4(8192 / 128, 512 / 64);
    gemm_mfma<0><<<g4, 256, 0, stream>>>(aobf, opwbf, opb, nullptr, nullptr,
                                         out_main, nullptr, nullptr, nullptr, E_DIM, E_DIM);
}